// Round 1
// baseline (218.737 us; speedup 1.0000x reference)
//
#include <hip/hip_runtime.h>
#include <hip/hip_bf16.h>
#include <hip/hip_fp16.h>

#define D_MODEL 1024
#define NH 16
#define HD 64
#define BATCH 2
#define SEQ 2048

typedef __attribute__((ext_vector_type(8))) short short8;
typedef __attribute__((ext_vector_type(4))) float floatx4;
typedef __attribute__((ext_vector_type(16))) float floatx16;
typedef __attribute__((ext_vector_type(8))) _Float16 half8;

static __device__ __forceinline__ short f2bf(float f) {
    __hip_bfloat16 h = __float2bfloat16(f);
    return *reinterpret_cast<short*>(&h);
}
static __device__ __forceinline__ unsigned int pk2bf(float a, float b) {
    float2 t; t.x = a; t.y = b;
    __hip_bfloat162 h2 = __float22bfloat162_rn(t);
    return *reinterpret_cast<unsigned int*>(&h2);
}
// v_permlane32_swap_b32: a.hi-lanes <-> b.lo-lanes (in place on both)
static __device__ __forceinline__ void pl32swap(unsigned &a, unsigned &b) {
    asm("v_permlane32_swap_b32 %0, %1" : "+v"(a), "+v"(b));
}
static __device__ __forceinline__ short8 mk8(unsigned a, unsigned b,
                                             unsigned c, unsigned d) {
    union { unsigned u[4]; short8 s; } t;
    t.u[0] = a; t.u[1] = b; t.u[2] = c; t.u[3] = d;
    return t.s;
}

#define GLDS(gp, lp) __builtin_amdgcn_global_load_lds( \
    (const __attribute__((address_space(1))) void*)(gp), \
    (__attribute__((address_space(3))) void*)(lp), 16, 0, 0)

// ---------------------------------------------------------------------------
// fused fp32 -> bf16 convert: x (4M), w_qkv (3M), w_fc (1M)
// ---------------------------------------------------------------------------
__global__ __launch_bounds__(256) void cvt_all(
    const float* __restrict__ x, const float* __restrict__ wq,
    const float* __restrict__ wf,
    short* __restrict__ Xb, short* __restrict__ Wqb, short* __restrict__ Wfb)
{
    int i = blockIdx.x * 256 + threadIdx.x;
    const float* src; short* dst; int off;
    if (i < 524288)      { src = x;  dst = Xb;  off = i; }
    else if (i < 917504) { src = wq; dst = Wqb; off = i - 524288; }
    else                 { src = wf; dst = Wfb; off = i - 917504; }
    float4 a = *reinterpret_cast<const float4*>(src + off * 8);
    float4 b = *reinterpret_cast<const float4*>(src + off * 8 + 4);
    short8 o;
    o[0] = f2bf(a.x); o[1] = f2bf(a.y); o[2] = f2bf(a.z); o[3] = f2bf(a.w);
    o[4] = f2bf(b.x); o[5] = f2bf(b.y); o[6] = f2bf(b.z); o[7] = f2bf(b.w);
    *reinterpret_cast<short8*>(dst + off * 8) = o;
}

// ---------------------------------------------------------------------------
// GEMM1: QKV projection. 128x128 tiles, BK=128 (8 iters, 64 MFMA/wave/drain),
// global_load_lds(16B) + XOR swizzle, XCD-clustered block mapping.
// Q*0.125*log2e -> [b,h,s,d]; K -> [b,h,s,d]; V -> [b,h,d,s].
// ---------------------------------------------------------------------------
__global__ __launch_bounds__(256) void qkv_gemm(
    const short* __restrict__ X, const short* __restrict__ W,
    const float* __restrict__ bias,
    short* __restrict__ Qs, short* __restrict__ Ks, short* __restrict__ Vt_g)
{
    __shared__ __align__(16) short As[128 * 128];   // 32 KB
    __shared__ __align__(16) short Bs[128 * 128];   // 32 KB
    const int tid = threadIdx.x;

    // XCD-clustered decode
    const int lin = blockIdx.x;
    const int g = lin & 7;
    const int loc = lin >> 3;         // 0..95
    const int mi = loc / 3;           // 0..31
    const int j3 = loc - mi * 3;      // 0..2
    const int m0 = mi * 128;
    const int n0 = (g + 8 * j3) * 128;
    const int bi = m0 >> 11, sl0 = m0 & 2047;

    const int w = tid >> 6, lane = tid & 63;
    const int quad = lane >> 4, l15 = lane & 15;
    const int wm2 = w >> 1, wn2 = w & 1;

    const int rg = lane >> 3;          // row in 8-row group
    const int sl = lane & 7;           // LDS 16B slot
    const int cg = sl ^ rg;            // swizzled global chunk

    floatx4 acc[4][4];
#pragma unroll
    for (int i = 0; i < 4; i++)
#pragma unroll
        for (int j = 0; j < 4; j++) acc[i][j] = (floatx4)0.0f;

    for (int k0 = 0; k0 < 1024; k0 += 128) {
        __syncthreads();
#pragma unroll
        for (int jj = 0; jj < 4; jj++) {
            int grp = w * 4 + jj;              // 16 groups of 8 rows
            int r = grp * 8 + rg;
#pragma unroll
            for (int kh = 0; kh < 2; kh++) {
                GLDS(&X[(size_t)(m0 + r) * 1024 + k0 + kh * 64 + cg * 8],
                     &As[grp * 1024 + kh * 512]);
                GLDS(&W[(size_t)(n0 + r) * 1024 + k0 + kh * 64 + cg * 8],
                     &Bs[grp * 1024 + kh * 512]);
            }
        }
        __syncthreads();
#pragma unroll
        for (int kk = 0; kk < 4; kk++) {
            const int kw = kk * 32 + quad * 8;
            const int base = (kw >> 6) * 512 +
                             ((((kw & 63) >> 3) ^ (l15 & 7)) * 8);
            short8 a[4], b[4];
#pragma unroll
            for (int t = 0; t < 4; t++) {
                int ra = wm2 * 64 + t * 16 + l15;
                int rb = wn2 * 64 + t * 16 + l15;
                a[t] = *reinterpret_cast<const short8*>(
                    &As[(ra >> 3) * 1024 + (ra & 7) * 64 + base]);
                b[t] = *reinterpret_cast<const short8*>(
                    &Bs[(rb >> 3) * 1024 + (rb & 7) * 64 + base]);
            }
#pragma unroll
            for (int mt = 0; mt < 4; mt++)
#pragma unroll
                for (int nt = 0; nt < 4; nt++)
                    acc[mt][nt] = __builtin_amdgcn_mfma_f32_16x16x32_bf16(
                        a[mt], b[nt], acc[mt][nt], 0, 0, 0);
        }
    }

    __syncthreads();
    short* EA = &As[0];      // [128][72] row-major bounce view (9216 shorts)
    short* T  = &As[0];      // [64][136] transposed view for V (8704 shorts)
#pragma unroll
    for (int half = 0; half < 2; half++) {
        const int colg0 = n0 + half * 64;
        const int h = colg0 / 192;
        const int t = (colg0 % 192) / 64;
        if (wn2 == half) {
#pragma unroll
            for (int nt = 0; nt < 4; nt++) {
                int jj = nt * 16 + l15;
                float bv = bias[colg0 + jj];
#pragma unroll
                for (int mt = 0; mt < 4; mt++) {
#pragma unroll
                    for (int r = 0; r < 4; r++) {
                        int ml = wm2 * 64 + mt * 16 + quad * 4 + r;
                        float v = acc[mt][nt][r] + bv;
                        if (t == 0) v *= 0.18033688f;   // 0.125 * log2(e)
                        if (t < 2) EA[ml * 72 + jj] = f2bf(v);
                        else       T[jj * 136 + ml] = f2bf(v);
                    }
                }
            }
        }
        __syncthreads();
        if (t < 2) {
            short* dst = (t == 0) ? Qs : Ks;
#pragma unroll
            for (int i = 0; i < 4; i++) {       // 128 rows x 8 chunks
                int c = tid + i * 256;
                int row = c >> 3, ck = c & 7;
                uint4 u = *reinterpret_cast<const uint4*>(&EA[row * 72 + ck * 8]);
                *reinterpret_cast<uint4*>(
                    &dst[((size_t)(bi * NH + h) * SEQ + sl0 + row) * HD + ck * 8]) = u;
            }
        } else {
#pragma unroll
            for (int i = 0; i < 4; i++) {       // 64 d-rows x 16 chunks
                int c = tid + i * 256;
                int d = c >> 4, ck = c & 15;
                uint4 u = *reinterpret_cast<const uint4*>(&T[d * 136 + ck * 8]);
                *reinterpret_cast<uint4*>(
                    &Vt_g[((size_t)(bi * NH + h) * HD + d) * SEQ + sl0 + ck * 8]) = u;
            }
        }
        __syncthreads();
    }
}

// ---------------------------------------------------------------------------
// Flash attention, LDS-free 32x32 MFMA version.
// Per wave: 64 q (2 q-tiles of 32). K-SPLIT x2 (khalf), 32-k tiles.
// QK^T = mfma_32x32x16(Kfrag, Qfrag) -> S^T: col=q(lane&31),
//   row=k=(reg&3)+8*(reg>>2)+4*hi. exp2 in-register, then T12:
//   cvt_pk pairs + v_permlane32_swap -> PV A-fragment (k = hi*8+j).
// K/Q/V fragments are direct 16B global loads (L1-shared across waves).
// No LDS, no barriers, no bank conflicts. l via ones-MFMA (same row layout
// as O). Output layout to Opart/lpart identical to previous version.
// ---------------------------------------------------------------------------
__global__ __launch_bounds__(256, 2) void attn_kernel(
    const short* __restrict__ Qs, const short* __restrict__ Ks,
    const short* __restrict__ Vt_g,
    _Float16* __restrict__ Opart, float* __restrict__ lpart)
{
    const int tid = threadIdx.x;
    const int w = tid >> 6, lane = tid & 63;
    const int hi = lane >> 5, l31 = lane & 31;
    const int bx = blockIdx.x;              // 16: qblk = bx>>1, khalf = bx&1
    const int khalf = bx & 1;
    const int q0 = (bx >> 1) * 256;
    const int h = blockIdx.y, bi = blockIdx.z;
    const int bh = bi * NH + h;
    const int kbase = bh * SEQ * HD;        // K/Q: [s][d]
    const int vbase = bh * HD * SEQ;        // V^T: [d][s]
    const int kt0 = khalf * (SEQ / 2);
    const int qw = q0 + w * 64;

    const short8 onesv = {(short)0x3F80, (short)0x3F80, (short)0x3F80, (short)0x3F80,
                          (short)0x3F80, (short)0x3F80, (short)0x3F80, (short)0x3F80};

    // Q fragments (B-operand): col = q = l31, k-elem d = c*16 + hi*8 + j
    short8 aq[2][4];
#pragma unroll
    for (int qt = 0; qt < 2; qt++) {
        const short* qp = Qs + kbase + (size_t)(qw + qt * 32 + l31) * HD + hi * 8;
#pragma unroll
        for (int c = 0; c < 4; c++)
            aq[qt][c] = *reinterpret_cast<const short8*>(qp + c * 16);
    }

    floatx16 o[2][2], ol[2];
#pragma unroll
    for (int qt = 0; qt < 2; qt++) {
        ol[qt] = (floatx16)0.0f;
        o[qt][0] = (floatx16)0.0f;
        o[qt][1] = (floatx16)0.0f;
    }

#pragma unroll 2
    for (int it = 0; it < SEQ / 2 / 32; it++) {   // 32 tiles of 32 k
        const int kt = kt0 + it * 32;
        // K fragments (A-operand): row = k = l31, d = c*16 + hi*8 + j
        const short* kp = Ks + kbase + (size_t)(kt + l31) * HD + hi * 8;
        short8 kf0 = *reinterpret_cast<const short8*>(kp);
        short8 kf1 = *reinterpret_cast<const short8*>(kp + 16);
        short8 kf2 = *reinterpret_cast<const short8*>(kp + 32);
        short8 kf3 = *reinterpret_cast<const short8*>(kp + 48);
        // V fragments (B-operand): col = d = dt*32 + l31, k = ch*16 + hi*8 + j
        const short* vp = Vt_g + vbase + (size_t)l31 * SEQ + kt + hi * 8;
        short8 vf00 = *reinterpret_cast<const short8*>(vp);                 // ch0 dt0
        short8 vf10 = *reinterpret_cast<const short8*>(vp + 16);            // ch1 dt0
        short8 vf01 = *reinterpret_cast<const short8*>(vp + 32 * SEQ);      // ch0 dt1
        short8 vf11 = *reinterpret_cast<const short8*>(vp + 32 * SEQ + 16); // ch1 dt1

#pragma unroll
        for (int qt = 0; qt < 2; qt++) {
            // S^T tile: D[k][q], k over 32, q over 32, d-contraction 64
            floatx16 s = (floatx16)0.0f;
            s = __builtin_amdgcn_mfma_f32_32x32x16_bf16(kf0, aq[qt][0], s, 0, 0, 0);
            s = __builtin_amdgcn_mfma_f32_32x32x16_bf16(kf1, aq[qt][1], s, 0, 0, 0);
            s = __builtin_amdgcn_mfma_f32_32x32x16_bf16(kf2, aq[qt][2], s, 0, 0, 0);
            s = __builtin_amdgcn_mfma_f32_32x32x16_bf16(kf3, aq[qt][3], s, 0, 0, 0);

            float p[16];
#pragma unroll
            for (int r = 0; r < 16; r++) p[r] = exp2f(s[r]);

            // T12: pack pairs, permlane32_swap to PV A-layout (k = hi*8+j)
            unsigned d0a = pk2bf(p[0], p[1]),   d2a = pk2bf(p[4], p[5]);
            unsigned d1a = pk2bf(p[2], p[3]),   d3a = pk2bf(p[6], p[7]);
            pl32swap(d0a, d2a);
            pl32swap(d1a, d3a);
            unsigned d0b = pk2bf(p[8], p[9]),   d2b = pk2bf(p[12], p[13]);
            unsigned d1b = pk2bf(p[10], p[11]), d3b = pk2bf(p[14], p[15]);
            pl32swap(d0b, d2b);
            pl32swap(d1b, d3b);
            short8 pa0 = mk8(d0a, d1a, d2a, d3a);   // k in [0,16)
            short8 pa1 = mk8(d0b, d1b, d2b, d3b);   // k in [16,32)

            o[qt][0] = __builtin_amdgcn_mfma_f32_32x32x16_bf16(pa0, vf00, o[qt][0], 0, 0, 0);
            o[qt][1] = __builtin_amdgcn_mfma_f32_32x32x16_bf16(pa0, vf01, o[qt][1], 0, 0, 0);
            o[qt][0] = __builtin_amdgcn_mfma_f32_32x32x16_bf16(pa1, vf10, o[qt][0], 0, 0, 0);
            o[qt][1] = __builtin_amdgcn_mfma_f32_32x32x16_bf16(pa1, vf11, o[qt][1], 0, 0, 0);
            ol[qt] = __builtin_amdgcn_mfma_f32_32x32x16_bf16(pa0, onesv, ol[qt], 0, 0, 0);
            ol[qt] = __builtin_amdgcn_mfma_f32_32x32x16_bf16(pa1, onesv, ol[qt], 0, 0, 0);
        }
    }

    // Epilogue: O rows q = (r&3)+8*(r>>2)+4*hi, cols d = dt*32 + l31
#pragma unroll
    for (int qt = 0; qt < 2; qt++) {
#pragma unroll
        for (int r = 0; r < 16; r++) {
            int ql = qw + qt * 32 + (r & 3) + 8 * (r >> 2) + 4 * hi;
            size_t base = (size_t)khalf * (4096u * 1024u) +
                          ((size_t)bi * SEQ + ql) * D_MODEL + h * HD;
            Opart[base + l31]      = (_Float16)o[qt][0][r];
            Opart[base + 32 + l31] = (_Float16)o[qt][1][r];
            if (l31 == 0)
                lpart[khalf * 65536 + bh * SEQ + ql] = ol[qt][r];
        }
    }
}

// ---------------------------------------------------------------------------
// combine: attnb[m][e] = bf16( (O1+O2)/(l1+l2) ). 8 elems/thread.
// ---------------------------------------------------------------------------
__global__ __launch_bounds__(256) void combine_kernel(
    const _Float16* __restrict__ O, const float* __restrict__ lp,
    short* __restrict__ attnb)
{
    int i = blockIdx.x * 256 + threadIdx.x;
    int m = i >> 7;
    int e0 = (i & 127) * 8;
    int bi = m >> 11, s = m & 2047, h = e0 >> 6;
    int bh = bi * NH + h;
    float l = lp[bh * SEQ + s] + lp[65536 + bh * SEQ + s];
    float rl = 1.0f / l;
    size_t off = (size_t)m * D_MODEL + e0;
    half8 a = *reinterpret_cast<const half8*>(O + off);
    half8 b = *reinterpret_cast<const half8*>(O + 4096u * 1024u + off);
    short8 out;
#pragma unroll
    for (int j = 0; j < 8; j++)
        out[j] = f2bf(((float)a[j] + (float)b[j]) * rl);
    *reinterpret_cast<short8*>(attnb + off) = out;
}

// ---------------------------------------------------------------------------
// GEMM2 (R16-exact): 128m x 64n, global_load_lds + XOR swizzle. fp32 out.
// ---------------------------------------------------------------------------
__global__ __launch_bounds__(256) void fc_gemm(
    const short* __restrict__ A, const short* __restrict__ W,
    const float* __restrict__ bias, float* __restrict__ out)
{
    __shared__ __align__(16) short As[128 * 64];
    __shared__ __align__(16) short Bs[64 * 64];
    const int tid = threadIdx.x;
    const int m0 = blockIdx.y * 128;
    const int n0 = blockIdx.x * 64;
    const int w = tid >> 6, lane = tid & 63;
    const int quad = lane >> 4, l15 = lane & 15;
    const int wm2 = w >> 1, wn2 = w & 1;

    const int rg = lane >> 3;
    const int sl = lane & 7;
    const int cg = sl ^ rg;

    floatx4 acc[4][2];
#pragma unroll
    for (int i = 0; i < 4; i++)
#pragma unroll
        for (int j = 0; j < 2; j++) acc[i][j] = (floatx4)0.0f;

    for (int k0 = 0; k0 < 1024; k0 += 64) {
        __syncthreads();
#pragma unroll
        for (int j = 0; j < 4; j++) {
            int g = w * 4 + j;
            int r = g * 8 + rg;
            GLDS(&A[(size_t)(m0 + r) * 1024 + k0 + cg * 8], &As[g * 512]);
        }
#pragma unroll
        for (int j = 0; j < 2; j++) {
            int g = w * 2 + j;
            int r = g * 8 + rg;
            GLDS(&W[(size_t)(n0 + r) * 1024 + k0 + cg * 8], &Bs[g * 512]);
        }
        __syncthreads();
#pragma unroll
        for (int kk = 0; kk < 2; kk++) {
            int swz = ((kk * 4 + quad) ^ (l15 & 7)) * 8;
            short8 a[4], b[2];
#pragma unroll
            for (int i = 0; i < 4; i++)
                a[i] = *reinterpret_cast<const short8*>(
                    &As[(wm2 * 64 + i * 16 + l15) * 64 + swz]);
#pragma unroll
            for (int j = 0; j < 2; j++)
                b[j] = *reinterpret_cast<const short8*>(
                    &Bs[(wn2 * 32 + j * 16 + l15) * 64 + swz]);
#pragma unroll
            for (int mt = 0; mt < 4; mt++)
#pragma unroll
                for (int nt = 0; nt < 2; nt++)
                    acc[mt][nt] = __builtin_amdgcn_mfma_f32_16x16x32_bf16(
                        a[mt], b[nt], acc[mt][nt], 0, 0, 0);
        }
    }

#pragma unroll
    for (int nt = 0; nt < 2; nt++) {
        int col = n0 + wn2 * 32 + nt * 16 + l15;
        float bv = bias[col];
#pragma unroll
        for (int mt = 0; mt < 4; mt++) {
#pragma unroll
            for (int r = 0; r < 4; r++) {
                int row = m0 + wm2 * 64 + mt * 16 + quad * 4 + r;
                out[row * 1024 + col] = acc[mt][nt][r] + bv;
            }
        }
    }
}

extern "C" void kernel_launch(void* const* d_in, const int* in_sizes, int n_in,
                              void* d_out, int out_size, void* d_ws, size_t ws_size,
                              hipStream_t stream) {
    const float* x     = (const float*)d_in[0];
    const float* w_qkv = (const float*)d_in[1];
    const float* b_qkv = (const float*)d_in[2];
    const float* w_fc  = (const float*)d_in[3];
    const float* b_fc  = (const float*)d_in[4];
    float* out = (float*)d_out;

    const size_t M1 = 1024u * 1024u;
    short* ws = (short*)d_ws;
    short* Qs    = ws;
    short* Ks    = ws + 4 * M1;
    short* Vt_g  = ws + 8 * M1;
    short* Wfb   = ws + 12 * M1;
    short* Xb    = ws + 13 * M1;
    short* Wqb   = ws + 17 * M1;
    _Float16* Opart = (_Float16*)(ws + 13 * M1);
    float* lpart = (float*)(ws + 21 * M1);
    short* attnb = Qs;   // Qs dead after attn

    cvt_all<<<4096, 256, 0, stream>>>(x, w_qkv, w_fc, Xb, Wqb, Wfb);
    qkv_gemm<<<768, 256, 0, stream>>>(Xb, Wqb, b_qkv, Qs, Ks, Vt_g);
    attn_kernel<<<dim3(16, 16, 2), 256, 0, stream>>>(Qs, Ks, Vt_g, Opart, lpart);
    combine_kernel<<<2048, 256, 0, stream>>>(Opart, lpart, attnb);
    fc_gemm<<<dim3(16, 32), 256, 0, stream>>>(attnb, Wfb, b_fc, out);
}